// Round 15
// baseline (641.325 us; speedup 1.0000x reference)
//
#include <hip/hip_runtime.h>
#include <hip/hip_bf16.h>
#include <cstdint>
#include <cstddef>

typedef __attribute__((ext_vector_type(8))) short s16x8;
typedef __attribute__((ext_vector_type(4))) float f32x4;
typedef __attribute__((ext_vector_type(8))) _Float16 h8;
typedef __attribute__((ext_vector_type(4))) _Float16 h4;

#define TT 2048
#define BB 4
#define EE 1024
#define HH 16
#define DD 64
#define MR 8192   // T*B rows

#define MFMA_BF16(a,b,c) __builtin_amdgcn_mfma_f32_16x16x32_bf16(a,b,c,0,0,0)
#define MFMA_F16(a,b,c)  __builtin_amdgcn_mfma_f32_16x16x32_f16(a,b,c,0,0,0)

__device__ __forceinline__ ushort f2bf(float f) {
  uint32_t u = __float_as_uint(f);
  u += 0x7fffu + ((u >> 16) & 1u);   // RNE
  return (ushort)(u >> 16);
}

// global -> LDS async copy, 16B per lane. LDS dest must be wave-uniform base + lane*16.
#define GL2L(g, l) __builtin_amdgcn_global_load_lds( \
    (__attribute__((address_space(1))) void*)(g), \
    (__attribute__((address_space(3))) void*)(l), 16, 0, 0)

// ---------------------------------------------------------------- cast fp32->bf16
__global__ void cast_f32_bf16(const float* __restrict__ in, ushort* __restrict__ out, int n4) {
  int stride = gridDim.x * blockDim.x;
  for (int i = blockIdx.x * blockDim.x + threadIdx.x; i < n4; i += stride) {
    float4 v = ((const float4*)in)[i];
    ushort4 o;
    o.x = f2bf(v.x); o.y = f2bf(v.y); o.z = f2bf(v.z); o.w = f2bf(v.w);
    ((ushort4*)out)[i] = o;
  }
}

// ---------------------------------------------------------------- QKV projection
// C[m][n] = sum_k A[m][k]*W[n][k] + bias[n];  m=(t*4+b), n = sec*1024 + h*64 + d
// Q scaled by 0.125*log2(e) (softmax computed with exp2) -> bf16 [b][h][t][d];
// K -> bf16 same; V -> f16 transposed [b][h][d][t].
__global__ __launch_bounds__(256) void gemm_qkv(
    const ushort* __restrict__ A, const ushort* __restrict__ W,
    const float* __restrict__ bias,
    ushort* __restrict__ Qb, ushort* __restrict__ Kb, ushort* __restrict__ Vt)
{
  __shared__ ushort As[128 * 32];
  __shared__ ushort Bs[128 * 32];
  const int K = EE;
  int tid = threadIdx.x;
  int bn = blockIdx.x, bm = blockIdx.y;
  int brow = bm * 128, bcol = bn * 128;
  int lane = tid & 63, wid = tid >> 6;
  int wm = wid >> 1, wn = wid & 1;
  int lr = lane & 15, kg = lane >> 4;

  f32x4 zero = {0.f, 0.f, 0.f, 0.f};
  f32x4 acc[4][4];
#pragma unroll
  for (int i = 0; i < 4; i++)
#pragma unroll
    for (int j = 0; j < 4; j++) acc[i][j] = zero;

  int r0 = tid >> 2, c0 = (tid & 3) * 8;
  const ushort* Abase = A + (size_t)brow * K;
  const ushort* Wbase = W + (size_t)bcol * K;

  for (int k0 = 0; k0 < K; k0 += 32) {
    __syncthreads();
    GL2L(Abase + (size_t)r0 * K + k0 + c0,        &As[tid * 8]);
    GL2L(Abase + (size_t)(r0 + 64) * K + k0 + c0, &As[(tid + 256) * 8]);
    GL2L(Wbase + (size_t)r0 * K + k0 + c0,        &Bs[tid * 8]);
    GL2L(Wbase + (size_t)(r0 + 64) * K + k0 + c0, &Bs[(tid + 256) * 8]);
    __syncthreads();
    s16x8 af[4], bfr[4];
#pragma unroll
    for (int i = 0; i < 4; i++) af[i]  = *(const s16x8*)&As[(wm * 64 + i * 16 + lr) * 32 + kg * 8];
#pragma unroll
    for (int j = 0; j < 4; j++) bfr[j] = *(const s16x8*)&Bs[(wn * 64 + j * 16 + lr) * 32 + kg * 8];
#pragma unroll
    for (int i = 0; i < 4; i++)
#pragma unroll
      for (int j = 0; j < 4; j++)
        acc[i][j] = MFMA_BF16(af[i], bfr[j], acc[i][j]);
  }

#pragma unroll
  for (int i = 0; i < 4; i++)
#pragma unroll
    for (int j = 0; j < 4; j++) {
      int n = bcol + wn * 64 + j * 16 + lr;
      float bv = bias[n];
      int sec = n >> 10;
      int hd = n & 1023;
      int h = hd >> 6, d = hd & 63;
#pragma unroll
      for (int e = 0; e < 4; e++) {
        int m = brow + wm * 64 + i * 16 + kg * 4 + e;
        int t = m >> 2, b = m & 3;
        float v = acc[i][j][e] + bv;
        size_t hoff = (size_t)(b * HH + h);
        if (sec == 0)      Qb[(hoff * TT + t) * DD + d] = f2bf(v * 0.180336880f); // 0.125*log2e
        else if (sec == 1) Kb[(hoff * TT + t) * DD + d] = f2bf(v);
        else { _Float16 hv = (_Float16)v; Vt[(hoff * DD + d) * TT + t] = *(ushort*)&hv; }
      }
    }
}

// ---------------------------------------------------------------- fused attention
// Skewed two-group pipeline. Block = (qt, b): 32 q-rows, 512 thr, 1 block/CU.
// Group A = waves 0-3 (one per SIMD), rows 0-15 / sc rows 0-15; group B =
// waves 4-7, rows 16-31 / sc rows 16-31. 3-superphase skew pairs DIFFERENT
// phases at every barrier: (A:QKT,B:SM), (A:SM,B:PV), (A:PV,B:QKT) -> each
// SIMD always hosts one MFMA/mem wave + one VALU/trans wave (m114 overlap).
// PV waves cover full-k for one d-tile: no partial reduction, 3 barriers/head.
__global__ __launch_bounds__(512) void attn_fused(
    const ushort* __restrict__ Qb, const ushort* __restrict__ Kb,
    const _Float16* __restrict__ Vt, ushort* __restrict__ attn,
    float* __restrict__ avgp)
{
  __shared__ __align__(16) _Float16 sc[32 * 2048];  // 128 KB, swizzle col ^ ((row&7)<<3)
  __shared__ float pmax[32][4];        // per-row, per-wave-in-group partial maxima
  __shared__ float invl[32];

  const int qt = blockIdx.x;      // 0..63
  const int b  = blockIdx.y;      // 0..3
  const int tid = threadIdx.x;
  const int lane = tid & 63;
  const int w = tid >> 6;         // wave 0..7
  const int grp = w >> 2;         // 0 = A, 1 = B (waves i%4 -> SIMD i: one A + one B per SIMD)
  const int wg = w & 3;           // wave within group
  const int m = lane & 15;
  const int kq = lane >> 4;       // frag k-chunk == C-layout row group
  const int rbase = grp * 16;                 // sc row base for this group
  const int t0 = qt * 32 + rbase;             // global q-row base for this group

  // per-thread avg accumulator, PACKED f16: group rows wg*4+u, cols (c*64+lane)*8+j
  h8 av[4][4];
#pragma unroll
  for (int u = 0; u < 4; u++)
#pragma unroll
    for (int c = 0; c < 4; c++)
#pragma unroll
      for (int j = 0; j < 8; j++) av[u][c][j] = (_Float16)0.f;

  // ---- phase bodies ------------------------------------------------------
  auto QKT = [&](int h) {
    const size_t bh = (size_t)b * HH + h;
    const ushort* qp = Qb + (bh * TT + t0) * DD;
    s16x8 q0 = *(const s16x8*)&qp[(size_t)m * DD + kq * 8];
    s16x8 q1 = *(const s16x8*)&qp[(size_t)m * DD + 32 + kq * 8];
    const ushort* kbase = Kb + bh * TT * DD;
    float mx0 = -3e38f;
#pragma unroll 4
    for (int i = 0; i < 32; ++i) {
      int nt = wg * 32 + i;                    // k-tile 0..127 (wave: 512 keys)
      const ushort* kr = kbase + (size_t)(nt * 16 + m) * DD + kq * 8;
      s16x8 a0 = *(const s16x8*)kr;
      s16x8 a1 = *(const s16x8*)(kr + 32);
      f32x4 c0 = {0.f, 0.f, 0.f, 0.f};
      c0 = MFMA_BF16(a0, q0, c0);
      c0 = MFMA_BF16(a1, q1, c0);
      // lane holds S[k = nt*16 + kq*4 + e][q = m] -> packed h4 write
      int ksw = (nt * 16 + kq * 4) ^ ((m & 7) << 3);
      h4 p0;
#pragma unroll
      for (int e = 0; e < 4; e++) { mx0 = fmaxf(mx0, c0[e]); p0[e] = (_Float16)c0[e]; }
      *(h4*)&sc[(size_t)(rbase + m) * 2048 + ksw] = p0;
    }
    mx0 = fmaxf(mx0, __shfl_xor(mx0, 16));
    mx0 = fmaxf(mx0, __shfl_xor(mx0, 32));
    if (lane < 16) pmax[rbase + m][wg] = mx0;
  };

  auto SM = [&](int h) {
    (void)h;
#pragma unroll
    for (int u = 0; u < 4; ++u) {
      int r = rbase + wg * 4 + u;
      _Float16* rp = &sc[(size_t)r * 2048];
      int xr = (r & 7) << 3;
      float mx = fmaxf(fmaxf(pmax[r][0], pmax[r][1]), fmaxf(pmax[r][2], pmax[r][3]));
      f32x4 lv0 = {0.f, 0.f, 0.f, 0.f};
      f32x4 lv1 = {0.f, 0.f, 0.f, 0.f};
      h8 eh[4];
#pragma unroll
      for (int c = 0; c < 4; ++c) {
        h8 t = *(const h8*)&rp[((c * 64 + lane) * 8) ^ xr];
        h8 e;
#pragma unroll
        for (int j = 0; j < 4; j++) { float ef = exp2f((float)t[j] - mx); lv0[j] += ef; e[j] = (_Float16)ef; }
#pragma unroll
        for (int j = 4; j < 8; j++) { float ef = exp2f((float)t[j] - mx); lv1[j - 4] += ef; e[j] = (_Float16)ef; }
        *(h8*)&rp[((c * 64 + lane) * 8) ^ xr] = e;
        eh[c] = e;
      }
      float l = ((lv0[0] + lv0[1]) + (lv0[2] + lv0[3]))
              + ((lv1[0] + lv1[1]) + (lv1[2] + lv1[3]));
#pragma unroll
      for (int o = 32; o; o >>= 1) l += __shfl_xor(l, o);
      float inv = 1.0f / l;
      if (lane == 0) invl[r] = inv;
      _Float16 hinv = (_Float16)inv;
#pragma unroll
      for (int c = 0; c < 4; ++c)
#pragma unroll
        for (int j = 0; j < 8; j++)
          av[u][c][j] += eh[c][j] * hinv;     // packs to v_pk_fma_f16
    }
  };

  auto PV = [&](int h) {
    const size_t bh = (size_t)b * HH + h;
    const _Float16* ap = &sc[(size_t)(rbase + m) * 2048];
    const _Float16* vb = Vt + bh * DD * TT + (size_t)(wg * 16 + m) * TT + kq * 8;
    int xr = (m & 7) << 3;
    f32x4 accA = {0.f, 0.f, 0.f, 0.f};
    f32x4 accB = {0.f, 0.f, 0.f, 0.f};
#pragma unroll 4
    for (int s = 0; s < 32; ++s) {
      int ka = s * 32 + kq * 8;
      int kb2 = 1024 + ka;
      h8 aA = *(const h8*)&ap[ka ^ xr];
      h8 aB = *(const h8*)&ap[kb2 ^ xr];
      h8 vA = *(const h8*)(vb + s * 32);
      h8 vB = *(const h8*)(vb + 1024 + s * 32);
      accA = MFMA_F16(aA, vA, accA);
      accB = MFMA_F16(aB, vB, accB);
    }
#pragma unroll
    for (int e = 0; e < 4; e++) {
      int ql = kq * 4 + e;
      float v0 = (accA[e] + accB[e]) * invl[rbase + ql];
      attn[((size_t)(t0 + ql) * BB + b) * EE + h * DD + wg * 16 + m] = f2bf(v0);
    }
  };

  // ---- skewed schedule: 50 superphases, uniform barriers -----------------
  // A at s: ss=s;   op = ss%3: 0=QKT(h), 1=SM(h), 2=PV(h), h=ss/3  (ss<48)
  // B at s: ss=s-2 (2-superphase skew)
  for (int s = 0; s < 50; ++s) {
    int ss = grp ? (s - 2) : s;
    if (ss >= 0 && ss < 48) {
      int h = ss / 3;
      int op = ss - h * 3;
      if (op == 0)      QKT(h);
      else if (op == 1) SM(h);
      else              PV(h);
    }
    __syncthreads();
  }

  // ---- write avg once: row t0 + wg*4+u, cols (c*64+lane)*8 .. +7
#pragma unroll
  for (int u = 0; u < 4; ++u) {
    float* gp = avgp + ((size_t)b * TT + t0 + wg * 4 + u) * TT;
#pragma unroll
    for (int c = 0; c < 4; ++c) {
      int cb = (c * 64 + lane) * 8;
      float4 o0 = {(float)av[u][c][0] * 0.0625f, (float)av[u][c][1] * 0.0625f,
                   (float)av[u][c][2] * 0.0625f, (float)av[u][c][3] * 0.0625f};
      float4 o1 = {(float)av[u][c][4] * 0.0625f, (float)av[u][c][5] * 0.0625f,
                   (float)av[u][c][6] * 0.0625f, (float)av[u][c][7] * 0.0625f};
      ((float4*)(gp + cb))[0] = o0;
      ((float4*)(gp + cb))[1] = o1;
    }
  }
}

// ---------------------------------------------------------------- output projection
__global__ __launch_bounds__(256) void gemm_out(
    const ushort* __restrict__ A, const ushort* __restrict__ W,
    const float* __restrict__ bias, float* __restrict__ out)
{
  __shared__ ushort As[128 * 32];
  __shared__ ushort Bs[128 * 32];
  const int K = EE;
  int tid = threadIdx.x;
  int bn = blockIdx.x, bm = blockIdx.y;
  int brow = bm * 128, bcol = bn * 128;
  int lane = tid & 63, wid = tid >> 6;
  int wm = wid >> 1, wn = wid & 1;
  int lr = lane & 15, kg = lane >> 4;

  f32x4 zero = {0.f, 0.f, 0.f, 0.f};
  f32x4 acc[4][4];
#pragma unroll
  for (int i = 0; i < 4; i++)
#pragma unroll
    for (int j = 0; j < 4; j++) acc[i][j] = zero;

  int r0 = tid >> 2, c0 = (tid & 3) * 8;
  const ushort* Abase = A + (size_t)brow * K;
  const ushort* Wbase = W + (size_t)bcol * K;

  for (int k0 = 0; k0 < K; k0 += 32) {
    __syncthreads();
    GL2L(Abase + (size_t)r0 * K + k0 + c0,        &As[tid * 8]);
    GL2L(Abase + (size_t)(r0 + 64) * K + k0 + c0, &As[(tid + 256) * 8]);
    GL2L(Wbase + (size_t)r0 * K + k0 + c0,        &Bs[tid * 8]);
    GL2L(Wbase + (size_t)(r0 + 64) * K + k0 + c0, &Bs[(tid + 256) * 8]);
    __syncthreads();
    s16x8 af[4], bfr[4];
#pragma unroll
    for (int i = 0; i < 4; i++) af[i]  = *(const s16x8*)&As[(wm * 64 + i * 16 + lr) * 32 + kg * 8];
#pragma unroll
    for (int j = 0; j < 4; j++) bfr[j] = *(const s16x8*)&Bs[(wn * 64 + j * 16 + lr) * 32 + kg * 8];
#pragma unroll
    for (int i = 0; i < 4; i++)
#pragma unroll
      for (int j = 0; j < 4; j++)
        acc[i][j] = MFMA_BF16(af[i], bfr[j], acc[i][j]);
  }

#pragma unroll
  for (int i = 0; i < 4; i++)
#pragma unroll
    for (int j = 0; j < 4; j++) {
      int n = bcol + wn * 64 + j * 16 + lr;
      float bv = bias[n];
#pragma unroll
      for (int e = 0; e < 4; e++) {
        int m = brow + wm * 64 + i * 16 + kg * 4 + e;
        out[(size_t)m * EE + n] = acc[i][j][e] + bv;
      }
    }
}

// ---------------------------------------------------------------- launch
extern "C" void kernel_launch(void* const* d_in, const int* in_sizes, int n_in,
                              void* d_out, int out_size, void* d_ws, size_t ws_size,
                              hipStream_t stream) {
  const float* x  = (const float*)d_in[0];
  const float* w1 = (const float*)d_in[1];
  const float* b1 = (const float*)d_in[2];
  const float* w2 = (const float*)d_in[3];
  const float* b2 = (const float*)d_in[4];
  float* out = (float*)d_out;
  float* avg = out + (size_t)MR * EE;

  char* p = (char*)d_ws;
  ushort* Xb   = (ushort*)p; p += (size_t)MR * EE * 2;
  ushort* W1b  = (ushort*)p; p += (size_t)3 * EE * EE * 2;
  ushort* W2b  = (ushort*)p; p += (size_t)EE * EE * 2;
  ushort* Qb   = (ushort*)p; p += (size_t)BB * HH * TT * DD * 2;
  ushort* Kb   = (ushort*)p; p += (size_t)BB * HH * TT * DD * 2;
  ushort* Vt   = (ushort*)p; p += (size_t)BB * HH * TT * DD * 2;
  ushort* attn = (ushort*)p; p += (size_t)MR * EE * 2;
  (void)ws_size;

  cast_f32_bf16<<<1024, 256, 0, stream>>>(x,  Xb,  MR * EE / 4);
  cast_f32_bf16<<<512,  256, 0, stream>>>(w1, W1b, 3 * EE * EE / 4);
  cast_f32_bf16<<<256,  256, 0, stream>>>(w2, W2b, EE * EE / 4);
  gemm_qkv<<<dim3(24, 64), 256, 0, stream>>>(Xb, W1b, b1, Qb, Kb, Vt);
  attn_fused<<<dim3(TT / 32, BB), 512, 0, stream>>>(Qb, Kb, (const _Float16*)Vt, attn, avg);
  gemm_out<<<dim3(8, 64), 256, 0, stream>>>(attn, W2b, b2, out);
}